// Round 12
// baseline (1376.260 us; speedup 1.0000x reference)
//
#include <hip/hip_runtime.h>
#include <stdint.h>

// ---------------------------------------------------------------------------
// ConditionalDecoder: emb-gather -> LSTM x2 -> FiLM -> vocab GEMM
// B=16, T=256, V=32000, E=H=Z=256, 4H=1024
// Round 12: everything in one 512-block dataflow kernel.
//   roles: [0-15] X0 projection (xb -> X0, flagX)
//          [16-31] L0 recurrence (X0 -> h1b, flagA; gated on flagX)
//          [32-47] X1 projection (h1b -> X1, flagB; gated on flagA)
//          [48-63] L1 recurrence (X1 -> filmb, flagC; gated on flagB)
//          [64-511] vocab GEMM workers (filmb @ Wout^T + bout -> d_out),
//                   16000 tiles (M=64,N=128), q-major, gated on flagC.
//   512 blocks x 512 thr = exactly 2 blocks/CU co-resident (VGPR<=128
//   enforced by launch_bounds) -> spin-waits cannot deadlock.
//   LSTM per-step math unchanged from r9 (g bf16 + i,f,o fp8, W in regs).
// ---------------------------------------------------------------------------

#define B_  16
#define T_  256
#define H_  256
#define V_  32000
#define G4  1024

#define LTPB 512   // 8 waves
#define FSTR 32    // flag stride in ints (one 128B line per flag)
#define NVW  448   // vocab worker blocks
#define SASTR 264  // sA row stride (u16): 528B -> 2-way-free A-frag reads

typedef unsigned short u16;
typedef unsigned long long u64;
typedef __attribute__((ext_vector_type(8))) short  short8;
typedef __attribute__((ext_vector_type(4))) short  short4v;
typedef __attribute__((ext_vector_type(4))) float  f32x4;

static __device__ __forceinline__ float bf2f(u16 u) {
  uint32_t i = ((uint32_t)u) << 16;
  return __builtin_bit_cast(float, i);
}
static __device__ __forceinline__ u16 f2bf(float f) {
  uint32_t i = __builtin_bit_cast(uint32_t, f);
  uint32_t lsb = (i >> 16) & 1u;
  i += 0x7fffu + lsb;
  return (u16)(i >> 16);
}
static __device__ __forceinline__ float sigf(float x) {
  return 1.0f / (1.0f + __expf(-x));
}
static __device__ __forceinline__ float tanhfast(float x) {
  return 1.0f - 2.0f / (1.0f + __expf(2.0f * x));
}

// OCP e4m3fn encode (bias 7, max 448, RNE). Same encoder for W-pack and h.
static __device__ __forceinline__ uint32_t f32_to_e4m3(float f) {
  uint32_t u = __builtin_bit_cast(uint32_t, f);
  uint32_t s = (u >> 24) & 0x80u;
  uint32_t mag = u & 0x7fffffffu;
  if (mag >= 0x43E00000u) return s | 0x7Eu;
  if (mag < 0x3C800000u) {
    float af = __builtin_bit_cast(float, mag);
    int q = (int)rintf(af * 512.0f);
    if (q >= 8) return s | 0x08u;
    return s | (uint32_t)q;
  }
  uint32_t lsb = (mag >> 20) & 1u;
  mag += 0x7ffffu + lsb;
  int e = (int)(mag >> 23) - 120;
  uint32_t m3 = (mag >> 20) & 7u;
  if (e >= 16) return s | 0x7Eu;
  return s | ((uint32_t)e << 3) | m3;
}

// ------------------------------ prep kernels -------------------------------

__global__ void k_convert(const float* __restrict__ src, u16* __restrict__ dst, int n) {
  int i = blockIdx.x * blockDim.x + threadIdx.x;
  int stride = gridDim.x * blockDim.x;
  for (; i < n; i += stride) dst[i] = f2bf(src[i]);
}

__global__ void k_addbias(const float* __restrict__ a, const float* __restrict__ b,
                          float* __restrict__ dst, int n) {
  int i = blockIdx.x * blockDim.x + threadIdx.x;
  if (i < n) dst[i] = a[i] + b[i];
}

__global__ void k_zeroi(int* __restrict__ p, int n) {
  int i = blockIdx.x * blockDim.x + threadIdx.x;
  if (i < n) p[i] = 0;
}

// Pack bf16 W frags for g gate: 16 frags/wave (8 waves).
__global__ void k_packWg(const float* __restrict__ Whh, u16* __restrict__ pk) {
  int i = blockIdx.x * blockDim.x + threadIdx.x;   // 8192
  int lane = i & 63;
  int fb = (i >> 6) & 15;
  int w  = i >> 10;
  int cb = fb >> 3, ks = fb & 7;
  int row = 512 + w * 32 + cb * 16 + (lane & 15);
  int kb  = ks * 32 + (lane >> 4) * 8;
  const float* src = Whh + (size_t)row * 256 + kb;
  short8 v;
  #pragma unroll
  for (int j = 0; j < 8; j++) v[j] = (short)f2bf(src[j]);
  *(short8*)(pk + (size_t)i * 8) = v;
}

// Pack fp8 W frags for i,f,o gates: 48 frags/wave (8 waves).
__global__ void k_packW8(const float* __restrict__ Whh, u64* __restrict__ pk) {
  int i = blockIdx.x * blockDim.x + threadIdx.x;   // 24576
  int lane = i & 63;
  int fo = (i >> 6) % 48;
  int w  = (i >> 6) / 48;
  int g8 = fo >> 4, cb = (fo >> 3) & 1, ks = fo & 7;
  int base = (g8 == 0) ? 0 : (g8 == 1 ? 256 : 768);
  int row = base + w * 32 + cb * 16 + (lane & 15);
  int kb  = ks * 32 + (lane >> 4) * 8;
  const float* src = Whh + (size_t)row * 256 + kb;
  u64 p = 0;
  #pragma unroll
  for (int j = 0; j < 8; j++)
    p |= ((u64)f32_to_e4m3(src[j])) << (8 * j);
  pk[i] = p;
}

// gamma = z@Wg.T + bg ; beta = z@Wb.T + bb
__global__ void k_film(const float* __restrict__ z,
                       const float* __restrict__ Wg, const float* __restrict__ bg,
                       const float* __restrict__ Wb, const float* __restrict__ bb,
                       float* __restrict__ gamma, float* __restrict__ beta) {
  int tid = blockIdx.x * blockDim.x + threadIdx.x;   // 8192
  int which = tid >> 12;
  int o = tid & 4095;
  int b = o >> 8, h = o & 255;
  const float* W  = which ? Wb : Wg;
  const float* bi = which ? bb : bg;
  float acc = bi[h];
  const float* zr = z + b * 256;
  const float* wr = W + h * 256;
  #pragma unroll 8
  for (int k = 0; k < 256; k++) acc += zr[k] * wr[k];
  (which ? beta : gamma)[o] = acc;
}

// x[b][t][:] = (seq[b][t]==0 ? 0 : emb[seq[b][t]])  as bf16
__global__ void k_gather(const int* __restrict__ seq, const float* __restrict__ emb,
                         u16* __restrict__ xb) {
  int i = blockIdx.x * blockDim.x + threadIdx.x;
  int n = B_ * T_ * (H_ / 4);
  if (i >= n) return;
  int e4 = i & 63;
  int bt = i >> 6;
  int t = bt & 255, b = bt >> 8;
  int row = seq[b * 257 + t];
  short4v p;
  if (row == 0) {
    p[0] = 0; p[1] = 0; p[2] = 0; p[3] = 0;
  } else {
    const f32x4 v = *(const f32x4*)(emb + (size_t)row * 256 + e4 * 4);
    p[0] = (short)f2bf(v[0]); p[1] = (short)f2bf(v[1]);
    p[2] = (short)f2bf(v[2]); p[3] = (short)f2bf(v[3]);
  }
  *(short4v*)(xb + (size_t)bt * 256 + e4 * 4) = p;
}

// ----------------------------- fused roles ---------------------------------

static __device__ __forceinline__ void lstm_role(
    const float* __restrict__ Xpre, const u16* __restrict__ WpkG,
    const u64* __restrict__ Wpk8, u16* __restrict__ outb,
    const float* __restrict__ gamma, const float* __restrict__ beta,
    int mode, int s, int* flagOut, const int* flagIn,
    u16 (*hbuf)[256], u64 (*h8buf)[32]) {
  const int tid  = threadIdx.x;
  const int lane = tid & 63;
  const int w    = tid >> 6;
  const int l15  = lane & 15;
  const int lhi  = lane >> 4;

  short8 wgm[16];
  {
    const u16* bp = WpkG + ((size_t)(w * 16) * 64 + lane) * 8;
    #pragma unroll
    for (int f = 0; f < 16; ++f)
      wgm[f] = *(const short8*)(bp + (size_t)f * 512);
  }
  u64 w8r[48];
  {
    const u64* p8 = Wpk8 + (size_t)(w * 48) * 64 + lane;
    #pragma unroll
    for (int f = 0; f < 48; ++f)
      w8r[f] = p8[(size_t)f * 64];
  }

  const int col0 = w * 32 + l15;
  const int col1 = col0 + 16;
  float cs0 = 0.f, cs1 = 0.f;
  float gm0 = 1.f, gm1 = 1.f, bt0 = 0.f, bt1 = 0.f;
  if (mode) {
    gm0 = gamma[s * 256 + col0]; bt0 = beta[s * 256 + col0];
    gm1 = gamma[s * 256 + col1]; bt1 = beta[s * 256 + col1];
  }

  if (flagIn) {
    if (tid == 0) {
      while (__hip_atomic_load(flagIn, __ATOMIC_RELAXED,
                               __HIP_MEMORY_SCOPE_AGENT) < 1) { }
    }
    __syncthreads();
    __builtin_amdgcn_fence(__ATOMIC_ACQUIRE, "agent");
  }

  const float* xptr = Xpre + (size_t)s * T_ * 1024 + (size_t)(w * 16 + l15) * 8;

  // ---- t = 0 ----
  f32x4 xa = *(const f32x4*)(xptr);
  f32x4 xg = *(const f32x4*)(xptr + 4);
  {
    float cn0 = sigf(xa[2]) * cs0 + sigf(xa[0]) * tanhfast(xg[0]);
    float hn0 = sigf(xg[2]) * tanhfast(cn0);
    cs0 = cn0;
    float cn1 = sigf(xa[3]) * cs1 + sigf(xa[1]) * tanhfast(xg[1]);
    float hn1 = sigf(xg[3]) * tanhfast(cn1);
    cs1 = cn1;
    u16 h0 = f2bf(hn0), h1 = f2bf(hn1);
    if (lhi == 0) {
      hbuf[0][col0] = h0;
      hbuf[0][col1] = h1;
      ((uint8_t*)h8buf[0])[col0] = (uint8_t)f32_to_e4m3(hn0);
      ((uint8_t*)h8buf[0])[col1] = (uint8_t)f32_to_e4m3(hn1);
      outb[(size_t)(s * T_) * 256 + col0] = mode ? f2bf(gm0 * hn0 + bt0) : h0;
      outb[(size_t)(s * T_) * 256 + col1] = mode ? f2bf(gm1 * hn1 + bt1) : h1;
    }
  }
  asm volatile("s_waitcnt lgkmcnt(0)" ::: "memory");
  __builtin_amdgcn_sched_barrier(0);
  __builtin_amdgcn_s_barrier();
  __builtin_amdgcn_sched_barrier(0);

  xa = *(const f32x4*)(xptr + 1024);
  xg = *(const f32x4*)(xptr + 1024 + 4);

  for (int t = 1; t < T_; ++t) {
    if (flagIn && (t & 15) == 15 && (t + 1) < T_) {
      const int need = ((t + 1) >> 4) + 1;
      if (tid == 0) {
        while (__hip_atomic_load(flagIn, __ATOMIC_RELAXED,
                                 __HIP_MEMORY_SCOPE_AGENT) < need) { }
      }
      __syncthreads();
      __builtin_amdgcn_fence(__ATOMIC_ACQUIRE, "agent");
    }

    const float* xn = xptr + (size_t)((t + 1 < T_) ? t + 1 : t) * 1024;
    f32x4 na = *(const f32x4*)(xn);
    f32x4 ng = *(const f32x4*)(xn + 4);

    const u16* hrd  = hbuf[(t + 1) & 1];
    const u64* h8rd = h8buf[(t + 1) & 1];

    f32x4 aI[2], aF[2], aG[2], aO[2];
    #pragma unroll
    for (int i = 0; i < 2; ++i) {
      aI[i] = (f32x4){0.f, 0.f, 0.f, 0.f};
      aF[i] = (f32x4){0.f, 0.f, 0.f, 0.f};
      aG[i] = (f32x4){0.f, 0.f, 0.f, 0.f};
      aO[i] = (f32x4){0.f, 0.f, 0.f, 0.f};
    }
    #pragma unroll
    for (int ks = 0; ks < 8; ++ks) {
      short8 a  = *(const short8*)&hrd[ks * 32 + lhi * 8];
      u64    a8 = h8rd[ks * 4 + lhi];
      aG[0] = __builtin_amdgcn_mfma_f32_16x16x32_bf16(a, wgm[ks],     aG[0], 0, 0, 0);
      aG[1] = __builtin_amdgcn_mfma_f32_16x16x32_bf16(a, wgm[8 + ks], aG[1], 0, 0, 0);
      aI[0] = __builtin_amdgcn_mfma_f32_16x16x32_fp8_fp8((long)a8, (long)w8r[ks],      aI[0], 0, 0, 0);
      aI[1] = __builtin_amdgcn_mfma_f32_16x16x32_fp8_fp8((long)a8, (long)w8r[8 + ks],  aI[1], 0, 0, 0);
      aF[0] = __builtin_amdgcn_mfma_f32_16x16x32_fp8_fp8((long)a8, (long)w8r[16 + ks], aF[0], 0, 0, 0);
      aF[1] = __builtin_amdgcn_mfma_f32_16x16x32_fp8_fp8((long)a8, (long)w8r[24 + ks], aF[1], 0, 0, 0);
      aO[0] = __builtin_amdgcn_mfma_f32_16x16x32_fp8_fp8((long)a8, (long)w8r[32 + ks], aO[0], 0, 0, 0);
      aO[1] = __builtin_amdgcn_mfma_f32_16x16x32_fp8_fp8((long)a8, (long)w8r[40 + ks], aO[1], 0, 0, 0);
    }

    float iv0 = aI[0][0] + xa[0], iv1 = aI[1][0] + xa[1];
    float fv0 = aF[0][0] + xa[2], fv1 = aF[1][0] + xa[3];
    float gv0 = aG[0][0] + xg[0], gv1 = aG[1][0] + xg[1];
    float ov0 = aO[0][0] + xg[2], ov1 = aO[1][0] + xg[3];

    float cn0 = sigf(fv0) * cs0 + sigf(iv0) * tanhfast(gv0);
    float hn0 = sigf(ov0) * tanhfast(cn0);
    cs0 = cn0;
    float cn1 = sigf(fv1) * cs1 + sigf(iv1) * tanhfast(gv1);
    float hn1 = sigf(ov1) * tanhfast(cn1);
    cs1 = cn1;

    u16 h0 = f2bf(hn0), h1 = f2bf(hn1);
    if (lhi == 0) {
      hbuf[t & 1][col0] = h0;
      hbuf[t & 1][col1] = h1;
      ((uint8_t*)h8buf[t & 1])[col0] = (uint8_t)f32_to_e4m3(hn0);
      ((uint8_t*)h8buf[t & 1])[col1] = (uint8_t)f32_to_e4m3(hn1);
      outb[((size_t)(s * T_ + t)) * 256 + col0] = mode ? f2bf(gm0 * hn0 + bt0) : h0;
      outb[((size_t)(s * T_ + t)) * 256 + col1] = mode ? f2bf(gm1 * hn1 + bt1) : h1;
    }

    if (flagOut && (t & 15) == 15) {
      __syncthreads();
      if (tid == 0) {
        __builtin_amdgcn_fence(__ATOMIC_RELEASE, "agent");
        __hip_atomic_store(flagOut, t + 1, __ATOMIC_RELAXED,
                           __HIP_MEMORY_SCOPE_AGENT);
      }
    } else {
      asm volatile("s_waitcnt lgkmcnt(0)" ::: "memory");
      __builtin_amdgcn_sched_barrier(0);
      __builtin_amdgcn_s_barrier();
      __builtin_amdgcn_sched_barrier(0);
    }

    xa = na;
    xg = ng;
  }
}

// gate-projection worker: dst(s, t0..t0+15, :) = src rows @ W^T + bias (permuted)
static __device__ __forceinline__ void proj_role(
    const u16* __restrict__ src, const u16* __restrict__ Wb_,
    const float* __restrict__ bias, float* __restrict__ dst,
    int s, const int* flagIn, int* flagOut) {
  const int tid  = threadIdx.x;
  const int lane = tid & 63;
  const int w    = tid >> 6;
  const int l15  = lane & 15;
  const int lhi  = lane >> 4;

  for (int tc = 0; tc < 16; ++tc) {
    if (flagIn) {
      const int need = (tc + 1) * 16;
      if (tid == 0) {
        while (__hip_atomic_load(flagIn, __ATOMIC_RELAXED,
                                 __HIP_MEMORY_SCOPE_AGENT) < need) { }
      }
      __syncthreads();
      __builtin_amdgcn_fence(__ATOMIC_ACQUIRE, "agent");
    }

    const int t0 = tc * 16;
    short8 afr[8];
    #pragma unroll
    for (int ks = 0; ks < 8; ++ks)
      afr[ks] = *(const short8*)(src + ((size_t)(s * T_ + t0 + l15)) * 256 + ks * 32 + lhi * 8);

    #pragma unroll
    for (int nt = 0; nt < 8; ++nt) {
      const int colb = w * 128 + nt * 16 + l15;
      f32x4 acc = (f32x4){0.f, 0.f, 0.f, 0.f};
      const u16* bp = Wb_ + (size_t)colb * 256 + lhi * 8;
      #pragma unroll
      for (int ks = 0; ks < 8; ++ks) {
        short8 bf = *(const short8*)(bp + ks * 32);
        acc = __builtin_amdgcn_mfma_f32_16x16x32_bf16(afr[ks], bf, acc, 0, 0, 0);
      }
      const int g = colb >> 8, r = colb & 255;
      const int ocol = (r >> 5) * 128 + (r & 15) * 8 + g * 2 + ((r >> 4) & 1);
      const float bv = bias[colb];
      #pragma unroll
      for (int i = 0; i < 4; ++i) {
        int trow = t0 + lhi * 4 + i;
        dst[((size_t)(s * T_ + trow)) * 1024 + ocol] = acc[i] + bv;
      }
    }

    __syncthreads();
    if (tid == 0) {
      __builtin_amdgcn_fence(__ATOMIC_RELEASE, "agent");
      __hip_atomic_store(flagOut, tc + 1, __ATOMIC_RELAXED,
                         __HIP_MEMORY_SCOPE_AGENT);
    }
  }
}

// vocab worker: 16000 tiles (M=64, N=128), q-major, gated on flagC[s] >= q*64+64
static __device__ __forceinline__ void vocab_role(
    const u16* __restrict__ filmb, const u16* __restrict__ Wo,
    const float* __restrict__ bout, float* __restrict__ out,
    const int* __restrict__ flagC, int wid, u16* __restrict__ sA) {
  const int tid  = threadIdx.x;
  const int lane = tid & 63;
  const int w    = tid >> 6;
  const int l15  = lane & 15;
  const int lhi  = lane >> 4;

  for (int n = wid; n < 16000; n += NVW) {
    const int q   = n / 4000;
    const int rem = n - q * 4000;
    const int s   = rem / 250;
    const int nt  = rem - s * 250;
    const int need = q * 64 + 64;
    if (tid == 0) {
      while (__hip_atomic_load(&flagC[s * FSTR], __ATOMIC_RELAXED,
                               __HIP_MEMORY_SCOPE_AGENT) < need) { }
    }
    __syncthreads();   // also WAR-protects sA from previous tile
    __builtin_amdgcn_fence(__ATOMIC_ACQUIRE, "agent");

    const int m0 = s * 256 + q * 64;
    const int n0 = nt * 128;

    // stage A: filmb rows [m0, m0+64), 256 cols bf16
    {
      const int r = tid >> 3, c = tid & 7;
      const u16* srow = filmb + (size_t)(m0 + r) * 256 + c * 8;
      #pragma unroll
      for (int it = 0; it < 4; ++it)
        *(short8*)&sA[r * SASTR + c * 8 + it * 64] = *(const short8*)(srow + it * 64);
    }
    __syncthreads();

    const int colb = n0 + w * 16 + l15;
    short8 bfr[8];
    #pragma unroll
    for (int ks = 0; ks < 8; ++ks)
      bfr[ks] = *(const short8*)(Wo + (size_t)colb * 256 + ks * 32 + lhi * 8);

    f32x4 acc[4];
    #pragma unroll
    for (int mi = 0; mi < 4; ++mi) acc[mi] = (f32x4){0.f, 0.f, 0.f, 0.f};
    #pragma unroll
    for (int ks = 0; ks < 8; ++ks) {
      #pragma unroll
      for (int mi = 0; mi < 4; ++mi) {
        short8 a = *(const short8*)&sA[(mi * 16 + l15) * SASTR + ks * 32 + lhi * 8];
        acc[mi] = __builtin_amdgcn_mfma_f32_16x16x32_bf16(a, bfr[ks], acc[mi], 0, 0, 0);
      }
    }

    const float bv = bout[colb];
    #pragma unroll
    for (int mi = 0; mi < 4; ++mi)
      #pragma unroll
      for (int i = 0; i < 4; ++i)
        out[(size_t)(m0 + mi * 16 + lhi * 4 + i) * V_ + colb] = acc[mi][i] + bv;
  }
}

__global__ __launch_bounds__(LTPB, 2) void k_fused(
    const u16* __restrict__ xb, float* __restrict__ X0, float* __restrict__ X1,
    const u16* __restrict__ WpG0, const u64* __restrict__ Wp80,
    const u16* __restrict__ WpG1, const u64* __restrict__ Wp81,
    const u16* __restrict__ Wih0b, const float* __restrict__ b01,
    const u16* __restrict__ Wih1b, const float* __restrict__ b11,
    const u16* __restrict__ Woutb, const float* __restrict__ bout,
    u16* __restrict__ h1b, u16* __restrict__ filmb, float* __restrict__ out,
    const float* __restrict__ gamma, const float* __restrict__ beta,
    int* __restrict__ flagX, int* __restrict__ flagA,
    int* __restrict__ flagB, int* __restrict__ flagC) {
  __shared__ u16 hbuf[2][256];
  __shared__ u64 h8buf[2][32];
  __shared__ u16 sA[64 * SASTR];

  const int bid = blockIdx.x;
  if (bid < 16) {
    proj_role(xb, Wih0b, b01, X0, bid, nullptr, &flagX[bid * FSTR]);
  } else if (bid < 32) {
    const int s = bid - 16;
    lstm_role(X0, WpG0, Wp80, h1b, gamma, beta, 0, s,
              &flagA[s * FSTR], &flagX[s * FSTR], hbuf, h8buf);
  } else if (bid < 48) {
    const int s = bid - 32;
    proj_role(h1b, Wih1b, b11, X1, s, &flagA[s * FSTR], &flagB[s * FSTR]);
  } else if (bid < 64) {
    const int s = bid - 48;
    lstm_role(X1, WpG1, Wp81, filmb, gamma, beta, 1, s,
              &flagC[s * FSTR], &flagB[s * FSTR], hbuf, h8buf);
  } else {
    vocab_role(filmb, Woutb, bout, out, flagC, bid - 64, sA);
  }
}

// ------------------------------ launcher -----------------------------------

extern "C" void kernel_launch(void* const* d_in, const int* in_sizes, int n_in,
                              void* d_out, int out_size, void* d_ws, size_t ws_size,
                              hipStream_t stream) {
  const float* z    = (const float*)d_in[0];
  const int*   seq  = (const int*)  d_in[1];
  const float* emb  = (const float*)d_in[2];
  const float* Wg   = (const float*)d_in[3];
  const float* bg   = (const float*)d_in[4];
  const float* Wb   = (const float*)d_in[5];
  const float* bb   = (const float*)d_in[6];
  const float* Wih0 = (const float*)d_in[7];
  const float* Whh0 = (const float*)d_in[8];
  const float* bih0 = (const float*)d_in[9];
  const float* bhh0 = (const float*)d_in[10];
  const float* Wih1 = (const float*)d_in[11];
  const float* Whh1 = (const float*)d_in[12];
  const float* bih1 = (const float*)d_in[13];
  const float* bhh1 = (const float*)d_in[14];
  const float* Wout = (const float*)d_in[15];
  const float* bout = (const float*)d_in[16];

  char* ws = (char*)d_ws;
  size_t off = 0;
  auto take = [&](size_t bytes) -> char* {
    char* p = ws + off;
    off = (off + bytes + 255) & ~(size_t)255;
    return p;
  };
  float* gamma  = (float*)take(B_ * H_ * 4);
  float* beta   = (float*)take(B_ * H_ * 4);
  float* b01    = (float*)take(G4 * 4);
  float* b11    = (float*)take(G4 * 4);
  u16*   Wih0b  = (u16*)  take((size_t)G4 * H_ * 2);
  u16*   Wih1b  = (u16*)  take((size_t)G4 * H_ * 2);
  u16*   WpG0   = (u16*)  take((size_t)8 * 16 * 64 * 8 * 2);
  u64*   Wp80   = (u64*)  take((size_t)8 * 48 * 64 * 8);
  u16*   WpG1   = (u16*)  take((size_t)8 * 16 * 64 * 8 * 2);
  u64*   Wp81   = (u64*)  take((size_t)8 * 48 * 64 * 8);
  u16*   Woutb  = (u16*)  take((size_t)V_ * H_ * 2);
  u16*   xb     = (u16*)  take((size_t)B_ * T_ * H_ * 2);
  float* X0     = (float*)take((size_t)B_ * T_ * G4 * 4);
  float* X1     = (float*)take((size_t)B_ * T_ * G4 * 4);
  u16*   h1b    = (u16*)  take((size_t)B_ * T_ * H_ * 2);
  u16*   filmb  = (u16*)  take((size_t)B_ * T_ * H_ * 2);
  int*   flagX  = (int*)  take(B_ * FSTR * 4);
  int*   flagA  = (int*)  take(B_ * FSTR * 4);
  int*   flagB  = (int*)  take(B_ * FSTR * 4);
  int*   flagC  = (int*)  take(B_ * FSTR * 4);
  (void)ws_size; (void)in_sizes; (void)n_in; (void)out_size;

  // prep
  k_convert<<<256, 256, 0, stream>>>(Wih0, Wih0b, G4 * H_);
  k_convert<<<256, 256, 0, stream>>>(Wih1, Wih1b, G4 * H_);
  k_convert<<<1024, 256, 0, stream>>>(Wout, Woutb, V_ * H_);
  k_packWg<<<32, 256, 0, stream>>>(Whh0, WpG0);
  k_packW8<<<96, 256, 0, stream>>>(Whh0, Wp80);
  k_packWg<<<32, 256, 0, stream>>>(Whh1, WpG1);
  k_packW8<<<96, 256, 0, stream>>>(Whh1, Wp81);
  k_addbias<<<4, 256, 0, stream>>>(bih0, bhh0, b01, G4);
  k_addbias<<<4, 256, 0, stream>>>(bih1, bhh1, b11, G4);
  k_zeroi<<<8, 256, 0, stream>>>(flagX, 4 * B_ * FSTR);   // flagX..flagC
  k_film<<<32, 256, 0, stream>>>(z, Wg, bg, Wb, bb, gamma, beta);
  k_gather<<<1024, 256, 0, stream>>>(seq, emb, xb);

  // fully fused pipeline: X0 || L0 || X1 || L1 || vocab GEMM
  k_fused<<<64 + NVW, LTPB, 0, stream>>>(
      xb, X0, X1, WpG0, Wp80, WpG1, Wp81, Wih0b, b01, Wih1b, b11,
      Woutb, bout, h1b, filmb, (float*)d_out, gamma, beta,
      flagX, flagA, flagB, flagC);
}